// Round 4
// baseline (427.815 us; speedup 1.0000x reference)
//
#include <hip/hip_runtime.h>

#define NN 50000
#define NE 800000
#define FIN 128
#define FH 64
#define FOUT 64
#define KC 1024
#define NB1 ((NN + 255) / 256)  // 196 chunks for the scan hierarchy

// ---------------------------------------------------------------------------
// Edge pass: in-degree histogram + pooled adjacency (stored TRANSPOSED:
// A_T[cv][cu] = A[cu][cv], so later column-ops over A become row-ops).
// ---------------------------------------------------------------------------
__global__ __launch_bounds__(256) void k_edge(const int* __restrict__ src,
                                              const int* __restrict__ dst,
                                              const int* __restrict__ cid,
                                              int* __restrict__ deg,
                                              float* __restrict__ AT) {
    int e = blockIdx.x * 256 + threadIdx.x;
    if (e >= NE) return;
    int s = src[e], d = dst[e];
    atomicAdd(&deg[d], 1);
    int cu = cid[s], cv = cid[d];
    if (cu != cv) AT[cv * KC + cu] = 1.0f;  // racing same-value stores: benign
}

// deg_p[t] = 1 + rowsum(A_T[t]); dinv_p = rsqrt.  256 thr/row for parallelism.
__global__ __launch_bounds__(256) void k_degp(const float* __restrict__ AT,
                                              float* __restrict__ dinvp) {
    __shared__ float sm[4];
    int t = blockIdx.x;
    int lane = threadIdx.x & 63, w = threadIdx.x >> 6;
    const float* row = AT + (size_t)t * KC;
    float s = 0.f;
    for (int i = threadIdx.x; i < KC; i += 256) s += row[i];
    for (int o = 32; o; o >>= 1) s += __shfl_down(s, o);
    if (lane == 0) sm[w] = s;
    __syncthreads();
    if (threadIdx.x == 0) dinvp[t] = rsqrtf(1.0f + sm[0] + sm[1] + sm[2] + sm[3]);
}

// per-node: dinv = rsqrt(deg+1); cluster counts
__global__ __launch_bounds__(256) void k_node(const int* __restrict__ deg,
                                              const int* __restrict__ cid,
                                              float* __restrict__ dinv,
                                              int* __restrict__ counts) {
    int i = blockIdx.x * 256 + threadIdx.x;
    if (i >= NN) return;
    dinv[i] = rsqrtf((float)deg[i] + 1.0f);
    atomicAdd(&counts[cid[i]], 1);
}

// --- reduce-then-scan hierarchy ---
__global__ __launch_bounds__(256) void k_scan1(const int* __restrict__ deg,
                                               int* __restrict__ partials) {
    __shared__ int ws[4];
    int i = blockIdx.x * 256 + threadIdx.x;
    int v = (i < NN) ? deg[i] : 0;
    for (int o = 32; o; o >>= 1) v += __shfl_down(v, o);
    int lane = threadIdx.x & 63, w = threadIdx.x >> 6;
    if (lane == 0) ws[w] = v;
    __syncthreads();
    if (threadIdx.x == 0)
        partials[blockIdx.x] = ws[0] + ws[1] + ws[2] + ws[3];
}

__global__ __launch_bounds__(256) void k_scan2(int* __restrict__ partials,
                                               int* __restrict__ rowptr) {
    __shared__ int sm[256];
    int t = threadIdx.x;
    int v = (t < NB1) ? partials[t] : 0;
    sm[t] = v;
    __syncthreads();
    for (int off = 1; off < 256; off <<= 1) {
        int u = (t >= off) ? sm[t - off] : 0;
        __syncthreads();
        sm[t] += u;
        __syncthreads();
    }
    if (t < NB1) partials[t] = sm[t] - v;  // exclusive
    if (t == 255) rowptr[NN] = sm[255];
}

__global__ __launch_bounds__(256) void k_scan3(int* __restrict__ deg,
                                               const int* __restrict__ partials,
                                               int* __restrict__ rowptr) {
    __shared__ int sm[256];
    int t = threadIdx.x;
    int i = blockIdx.x * 256 + t;
    int v = (i < NN) ? deg[i] : 0;
    sm[t] = v;
    __syncthreads();
    for (int off = 1; off < 256; off <<= 1) {
        int u = (t >= off) ? sm[t - off] : 0;
        __syncthreads();
        sm[t] += u;
        __syncthreads();
    }
    if (i < NN) {
        int r = partials[blockIdx.x] + sm[t] - v;
        rowptr[i] = r;
        deg[i] = r;  // fill cursor
    }
}

// Bucket-fill CSR column (source-id) list.
__global__ __launch_bounds__(256) void k_fill(const int* __restrict__ src,
                                              const int* __restrict__ dst,
                                              int* __restrict__ cursor,
                                              int* __restrict__ col) {
    int e = blockIdx.x * 256 + threadIdx.x;
    if (e >= NE) return;
    int pos = atomicAdd(&cursor[dst[e]], 1);
    col[pos] = src[e];
}

// h = x @ W1.  256 thr = 4 waves x 64 cols; 8 rows/thread (32 rows/block).
// W1 staged TRANSPOSED in LDS (pad +4) so 4 k-values/col = 1 ds_read_b128.
__global__ __launch_bounds__(256) void k_gemm1(const float* __restrict__ x,
                                               const float* __restrict__ W1,
                                               float* __restrict__ h) {
    __shared__ float Wt[FH][FIN + 4];  // 33792 B
    int t = threadIdx.x;
    for (int i = t; i < FIN * FH; i += 256) {
        int k = i >> 6, c = i & 63;
        Wt[c][k] = W1[i];
    }
    __syncthreads();
    int col = t & 63, grp = t >> 6;
    int row0 = blockIdx.x * 32 + grp * 8;
    const int L = FIN / 4;  // 32
    const float4* x4 = (const float4*)x;
    const float4* xp[8];
#pragma unroll
    for (int r = 0; r < 8; ++r) {
        int row = row0 + r;
        row = row < NN ? row : NN - 1;
        xp[r] = x4 + (size_t)row * L;
    }
    float acc[8] = {0.f, 0.f, 0.f, 0.f, 0.f, 0.f, 0.f, 0.f};
    for (int k4 = 0; k4 < L; ++k4) {
        float4 w = *(const float4*)&Wt[col][k4 * 4];
#pragma unroll
        for (int r = 0; r < 8; ++r) {
            float4 a = xp[r][k4];
            acc[r] = fmaf(a.x, w.x, fmaf(a.y, w.y, fmaf(a.z, w.z, fmaf(a.w, w.w, acc[r]))));
        }
    }
#pragma unroll
    for (int r = 0; r < 8; ++r) {
        int row = row0 + r;
        if (row < NN) h[(size_t)row * FH + col] = acc[r];
    }
}

// Gather aggregation + fused x1 epilogue + cluster-sum atomics.
__global__ __launch_bounds__(256) void k_gather(const int* __restrict__ rowptr,
                                                const int* __restrict__ col,
                                                const float* __restrict__ dinv,
                                                const float* __restrict__ h,
                                                const float* __restrict__ b1,
                                                const int* __restrict__ cid,
                                                float* __restrict__ x1,
                                                float* __restrict__ sums) {
    int lane = threadIdx.x & 63;
    int node = blockIdx.x * 4 + (threadIdx.x >> 6);
    if (node >= NN) return;
    int rp = rowptr[node], re = rowptr[node + 1];
    float acc = 0.f;
    for (int base = rp; base < re; base += 64) {
        int cnt = min(64, re - base);
        int s = (lane < cnt) ? col[base + lane] : 0;
        float w = (lane < cnt) ? dinv[s] : 0.f;
        for (int j = 0; j < cnt; ++j) {
            int ss = __shfl(s, j);
            float ww = __shfl(w, j);
            acc = fmaf(ww, h[(size_t)ss * FH + lane], acc);
        }
    }
    float di = dinv[node];
    float v = di * acc + di * di * h[(size_t)node * FH + lane] + b1[lane];
    v = fmaxf(v, 0.f);
    x1[(size_t)node * FH + lane] = v;
    unsafeAtomicAdd(&sums[(size_t)cid[node] * FH + lane], v);
}

// x_p = sums/counts; g[s] = dinv_p[s] * (x_p[s] @ W2)
__global__ __launch_bounds__(64) void k_pool(const float* __restrict__ sums,
                                             const int* __restrict__ counts,
                                             const float* __restrict__ W2,
                                             const float* __restrict__ dinvp,
                                             float* __restrict__ g) {
    __shared__ float xp[FH];
    int s = blockIdx.x, f = threadIdx.x;
    float cnt = fmaxf((float)counts[s], 1.0f);
    xp[f] = sums[(size_t)s * FH + f] / cnt;
    __syncthreads();
    float acc = 0.f;
    for (int j = 0; j < FH; ++j) acc = fmaf(xp[j], W2[j * FH + f], acc);
    g[(size_t)s * FH + f] = dinvp[s] * acc;
}

// xp2[t] = dinvp[t]*(g[t] + sum_s AT[t,s]*g[s]) + b2.
// One block (4 waves) per target row; each wave covers 256 sources; LDS reduce.
__global__ __launch_bounds__(256) void k_xp2(const float* __restrict__ AT,
                                             const float* __restrict__ g,
                                             const float* __restrict__ dinvp,
                                             const float* __restrict__ b2,
                                             float* __restrict__ xp2) {
    __shared__ float sm[4][FH];
    int t = blockIdx.x;
    int lane = threadIdx.x & 63, w = threadIdx.x >> 6;
    const float* row = AT + (size_t)t * KC;
    float acc = 0.f;
    int sb0 = w * 256;
    for (int sb = sb0; sb < sb0 + 256; sb += 64) {
        float a = row[sb + lane];
        for (int j = 0; j < 64; ++j) {
            float aj = __shfl(a, j);
            acc = fmaf(aj, g[(size_t)(sb + j) * FH + lane], acc);
        }
    }
    sm[w][lane] = acc;
    __syncthreads();
    if (w == 0) {
        acc = sm[0][lane] + sm[1][lane] + sm[2][lane] + sm[3][lane]
            + g[(size_t)t * FH + lane];  // self-loop
        xp2[(size_t)t * FH + lane] = dinvp[t] * acc + b2[lane];
    }
}

// out = xp2[cid] + relu(alpha) * (x1 @ W_skip + b_skip).  Same 8-row scheme.
__global__ __launch_bounds__(256) void k_final(const float* __restrict__ x1,
                                               const float* __restrict__ Wsk,
                                               const float* __restrict__ bsk,
                                               const float* __restrict__ xp2,
                                               const int* __restrict__ cid,
                                               const float* __restrict__ alpha,
                                               float* __restrict__ out) {
    __shared__ float Wt[FOUT][FH + 4];  // 17408 B
    int t = threadIdx.x;
    for (int i = t; i < FH * FOUT; i += 256) {
        int k = i >> 6, c = i & 63;
        Wt[c][k] = Wsk[i];
    }
    __syncthreads();
    float al = fmaxf(alpha[0], 0.f);
    int col = t & 63, grp = t >> 6;
    int row0 = blockIdx.x * 32 + grp * 8;
    const int L = FH / 4;  // 16
    const float4* x4 = (const float4*)x1;
    const float4* xp[8];
#pragma unroll
    for (int r = 0; r < 8; ++r) {
        int row = row0 + r;
        row = row < NN ? row : NN - 1;
        xp[r] = x4 + (size_t)row * L;
    }
    float acc[8] = {0.f, 0.f, 0.f, 0.f, 0.f, 0.f, 0.f, 0.f};
    for (int k4 = 0; k4 < L; ++k4) {
        float4 w = *(const float4*)&Wt[col][k4 * 4];
#pragma unroll
        for (int r = 0; r < 8; ++r) {
            float4 a = xp[r][k4];
            acc[r] = fmaf(a.x, w.x, fmaf(a.y, w.y, fmaf(a.z, w.z, fmaf(a.w, w.w, acc[r]))));
        }
    }
    float bb = bsk[col];
#pragma unroll
    for (int r = 0; r < 8; ++r) {
        int row = row0 + r;
        if (row < NN)
            out[(size_t)row * FOUT + col] =
                xp2[(size_t)cid[row] * FOUT + col] + al * (acc[r] + bb);
    }
}

extern "C" void kernel_launch(void* const* d_in, const int* in_sizes, int n_in,
                              void* d_out, int out_size, void* d_ws, size_t ws_size,
                              hipStream_t stream) {
    const float* x    = (const float*)d_in[0];
    const int*   ei   = (const int*)d_in[1];
    const int*   cid  = (const int*)d_in[2];
    const float* W1   = (const float*)d_in[3];
    const float* b1   = (const float*)d_in[4];
    const float* W2   = (const float*)d_in[5];
    const float* b2   = (const float*)d_in[6];
    const float* Wsk  = (const float*)d_in[7];
    const float* bsk  = (const float*)d_in[8];
    const float* alpha= (const float*)d_in[9];
    float* out = (float*)d_out;
    const int* src = ei;
    const int* dst = ei + NE;

    // workspace layout: zero-init region first (one memset covers it)
    char* ws = (char*)d_ws;
    size_t cur = 0;
    auto alloc = [&](size_t nb) { cur = (cur + 255) & ~(size_t)255; size_t o = cur; cur += nb; return o; };
    size_t o_sums = alloc((size_t)KC * FH * 4);
    size_t o_AT   = alloc((size_t)KC * KC * 4);
    size_t o_deg  = alloc((size_t)NN * 4);      // becomes CSR cursor after scan
    size_t o_cnt  = alloc((size_t)KC * 4);
    size_t zero_bytes = cur;
    size_t o_x1   = alloc((size_t)NN * FH * 4);
    size_t o_h    = alloc((size_t)NN * FH * 4);
    size_t o_rp   = alloc((size_t)(NN + 1) * 4);
    size_t o_col  = alloc((size_t)NE * 4);
    size_t o_dinv = alloc((size_t)NN * 4);
    size_t o_g    = alloc((size_t)KC * FH * 4);
    size_t o_xp2  = alloc((size_t)KC * FH * 4);
    size_t o_dinvp= alloc((size_t)KC * 4);
    size_t o_part = alloc((size_t)NB1 * 4);
    (void)ws_size; (void)in_sizes; (void)n_in; (void)out_size;

    float* sums = (float*)(ws + o_sums);
    float* AT   = (float*)(ws + o_AT);
    int*   deg  = (int*)(ws + o_deg);
    int*   cnt  = (int*)(ws + o_cnt);
    float* x1   = (float*)(ws + o_x1);
    float* h    = (float*)(ws + o_h);
    int*   rp   = (int*)(ws + o_rp);
    int*   colb = (int*)(ws + o_col);
    float* dinv = (float*)(ws + o_dinv);
    float* g    = (float*)(ws + o_g);
    float* xp2  = (float*)(ws + o_xp2);
    float* dinvp= (float*)(ws + o_dinvp);
    int*   part = (int*)(ws + o_part);

    hipMemsetAsync(d_ws, 0, zero_bytes, stream);

    k_edge  <<<(NE + 255) / 256, 256, 0, stream>>>(src, dst, cid, deg, AT);
    k_degp  <<<KC, 256, 0, stream>>>(AT, dinvp);
    k_node  <<<(NN + 255) / 256, 256, 0, stream>>>(deg, cid, dinv, cnt);
    k_scan1 <<<NB1, 256, 0, stream>>>(deg, part);
    k_scan2 <<<1, 256, 0, stream>>>(part, rp);
    k_scan3 <<<NB1, 256, 0, stream>>>(deg, part, rp);
    k_fill  <<<(NE + 255) / 256, 256, 0, stream>>>(src, dst, deg, colb);
    k_gemm1 <<<(NN + 31) / 32, 256, 0, stream>>>(x, W1, h);
    k_gather<<<(NN + 3) / 4, 256, 0, stream>>>(rp, colb, dinv, h, b1, cid, x1, sums);
    k_pool  <<<KC, 64, 0, stream>>>(sums, cnt, W2, dinvp, g);
    k_xp2   <<<KC, 256, 0, stream>>>(AT, g, dinvp, b2, xp2);
    k_final <<<(NN + 31) / 32, 256, 0, stream>>>(x1, Wsk, bsk, xp2, cid, alpha, out);
}